// Round 11
// baseline (273.526 us; speedup 1.0000x reference)
//
#include <hip/hip_runtime.h>
#include <cstdint>

#define K_SEL 4768
#define NBIN 4096
#define BUFCAP 512
#define SLICE 512
#define CAP 4608     // candidate capacity in k_seldec (>= worst observed ~4300)
#define CPT 18       // candidates per thread = CAP/256
#define TPAD 9216    // padded-triangular T words per (img,lvl)

struct P5 { const float* p[5]; };

__device__ __forceinline__ unsigned fsortkey(float f) {
  unsigned b = __float_as_uint(f);
  return (b & 0x80000000u) ? ~b : (b | 0x80000000u);
}

// ------- histogram of sortable-logit top-12 bits per (img,lvl): per-block partials ------
__global__ __launch_bounds__(256) void k_hist(P5 obj, unsigned* phist) {
  int p = blockIdx.y; int img = p / 5, lvl = p % 5;
  int f = 256 >> lvl; int n = 3 * f * f;
  __shared__ unsigned lh[NBIN];
  for (int b = threadIdx.x; b < NBIN; b += 256) lh[b] = 0;
  __syncthreads();
  const float4* src4 = (const float4*)(obj.p[lvl] + (size_t)img * n);
  int n4 = n >> 2;
  int chunk = (n4 + gridDim.x - 1) / gridDim.x;
  int e0 = blockIdx.x * chunk, e1 = min(n4, e0 + chunk);
  for (int e = e0 + threadIdx.x; e < e1; e += 256) {
    float4 v = src4[e];
    atomicAdd(&lh[fsortkey(v.x) >> 20], 1u);
    atomicAdd(&lh[fsortkey(v.y) >> 20], 1u);
    atomicAdd(&lh[fsortkey(v.z) >> 20], 1u);
    atomicAdd(&lh[fsortkey(v.w) >> 20], 1u);
  }
  __syncthreads();
  unsigned* dst = phist + ((size_t)(p * 8 + blockIdx.x)) * NBIN;
  for (int b = threadIdx.x; b < NBIN; b += 256) dst[b] = lh[b];   // unconditional: no pre-zero
}

// ------- sum partials, find threshold bin B; ALSO emit cumA[bin] = #elems in bins>bin ---
__global__ __launch_bounds__(256) void k_thresh(const unsigned* phist, int* Bthr,
                                                unsigned* cumA) {
  int p = blockIdx.x; int lvl = p % 5;
  unsigned kk = (lvl == 4) ? 768u : 1000u;
  __shared__ unsigned hsum[NBIN];
  __shared__ unsigned csum[256];
  __shared__ unsigned sAb[256];
  int c = threadIdx.x;
  unsigned tot[16];
#pragma unroll
  for (int k = 0; k < 16; ++k) tot[k] = 0;
  for (int g = 0; g < 8; ++g) {
    const unsigned* hp = phist + ((size_t)(p * 8 + g)) * NBIN + c * 16;
#pragma unroll
    for (int k = 0; k < 16; ++k) tot[k] += hp[k];
  }
  unsigned s = 0;
#pragma unroll
  for (int k = 0; k < 16; ++k) { hsum[c * 16 + k] = tot[k]; s += tot[k]; }
  csum[c] = s;
  __syncthreads();
  if (c == 0) {
    unsigned acc = 0; int B = 0;
    for (int cc = 255; cc >= 0; --cc) {
      if (acc + csum[cc] >= kk) {
        for (int b = 15; b >= 0; --b) {
          acc += hsum[cc * 16 + b];
          if (acc >= kk) { B = cc * 16 + b; break; }
        }
        break;
      }
      acc += csum[cc];
    }
    Bthr[p] = B;
    unsigned a2 = 0;                           // suffix sums of csum for cumA
    for (int cc = 255; cc >= 0; --cc) { sAb[cc] = a2; a2 += csum[cc]; }
  }
  __syncthreads();
  unsigned run = sAb[c];                       // cumA[bin] = run; run += hsum[bin], hi->lo
  unsigned* cg = cumA + (size_t)p * NBIN;
  for (int k = 15; k >= 0; --k) {
    int bin = c * 16 + k;
    cg[bin] = run;
    run += hsum[bin];
  }
}

// ------- gather: 32 blocks per p; per-block 512-key slice, plain-store count ------------
__global__ __launch_bounds__(256) void k_gather(P5 obj, const int* Bthr,
                                                unsigned* cntB, unsigned long long* ck) {
  int p = blockIdx.y; int img = p / 5, lvl = p % 5;
  int f = 256 >> lvl; int hw = f * f; int n = 3 * hw;
  int B = Bthr[p];
  int tid = threadIdx.x;
  int lane = tid & 63, wv = tid >> 6;
  int shift = 2 * (8 - lvl);
  const float4* src4 = (const float4*)(obj.p[lvl] + (size_t)img * n);
  int n4 = n >> 2;
  int chunk = (n4 + 31) >> 5;                  // gridDim.x == 32
  int e0 = blockIdx.x * chunk, e1 = min(n4, e0 + chunk);
  __shared__ unsigned long long buf[4][BUFCAP];
  __shared__ unsigned wTot[4];
  unsigned wc = 0;                             // wave-uniform running count
  for (int e = e0 + tid; e < e1; e += 256) {
    float4 v = src4[e];
    float vv[4] = {v.x, v.y, v.z, v.w};
#pragma unroll
    for (int j = 0; j < 4; ++j) {
      unsigned sv = fsortkey(vv[j]);
      bool pass = (int)(sv >> 20) >= B;
      unsigned long long m = __ballot(pass);
      if (m) {
        if (pass) {
          unsigned pos = wc + (unsigned)__popcll(m & ((1ULL << lane) - 1ULL));
          int ee = e * 4 + j;
          int a = ee >> shift;                 // ee / hw
          int r = ee & (hw - 1);               // ee % hw
          unsigned kidx = (unsigned)(r * 3 + a); // reference flatten order (y*W+x)*A + a
          unsigned long long key = ((unsigned long long)sv << 32) | (0xFFFFFFFFu - kidx);
          if (pos < BUFCAP) buf[wv][pos] = key; // overflow (pathological only): drop
        }
        wc += (unsigned)__popcll(m);
      }
    }
  }
  if (lane == 0) wTot[wv] = min(wc, (unsigned)BUFCAP);
  __syncthreads();
  unsigned myOff = 0;
  for (int x = 0; x < wv; ++x) myOff += wTot[x];
  unsigned tot4 = wTot[0] + wTot[1] + wTot[2] + wTot[3];
  unsigned long long* dst = ck + ((size_t)p * 32 + blockIdx.x) * SLICE;
  for (unsigned j = lane; j < wTot[wv]; j += 64) {
    unsigned gp = myOff + j;
    if (gp < SLICE) dst[gp] = buf[wv][j];      // coalesced slice flush, no atomics
  }
  if (tid == 0) cntB[p * 32 + blockIdx.x] = min(tot4, (unsigned)SLICE);
}

// ------- select+decode v2: counting-scatter rank (no O(Cc) scan), one block per p -------
// Cross-bucket rank comes FREE from the global histogram (cumA). Bin-B ties are bucketed
// by the next 12 key bits (h2 suffix-scan -> base2). Counting-sort scatter puts every
// candidate at its exact sorted region; exact rank = bucket_start + scan of a 1-5 entry
// bucket. Replaces 16 blocks x 4096 broadcast-LDS reads with 1 block x ~30 reads/thread.
__global__ __launch_bounds__(256) void k_seldec(P5 del, const float* anchors,
                                                const int* Bthr, const unsigned* cumA,
                                                const unsigned* cntB,
                                                const unsigned long long* ck,
                                                float* boxP, unsigned long long* keyP) {
  int p = blockIdx.x; int img = p / 5, lvl = p % 5;
  int kk = (lvl == 4) ? 768 : 1000;
  int soff = lvl * 1000;
  int tid = threadIdx.x;
  __shared__ unsigned long long skS[CAP];      // scatter target (sorted regions)
  __shared__ unsigned cur1[NBIN];              // bins>B cursors, init = cumA (consumed)
  __shared__ unsigned h2[NBIN];                // bin-B sub-hist -> base2 -> cursor
  __shared__ unsigned part[256];
  __shared__ unsigned offs[33];
  const unsigned* cA = cumA + (size_t)p * NBIN;
  for (int x = tid; x < NBIN; x += 256) { cur1[x] = cA[x]; h2[x] = 0u; }
  if (tid < 32) {                              // wave-parallel prefix of slice counts
    unsigned v = cntB[p * 32 + tid];
#pragma unroll
    for (int d = 1; d < 32; d <<= 1) {
      unsigned o = __shfl(v, tid - d);
      if (tid >= d) v += o;
    }
    offs[tid + 1] = v;
    if (tid == 0) offs[0] = 0;
  }
  __syncthreads();
  int B = Bthr[p];
  unsigned H = cA[B];                          // # candidates in bins > B
  int Cc = min((int)offs[32], CAP);
  // ---- stage my candidates into registers (binary-search slice lookup) ----
  unsigned long long key_[CPT];
#pragma unroll
  for (int k = 0; k < CPT; ++k) {
    int x = tid + k * 256;
    key_[k] = 0ULL;
    if (x < Cc) {
      int lo = 0;
#pragma unroll
      for (int d = 16; d; d >>= 1)
        if (offs[lo + d] <= (unsigned)x) lo += d;
      key_[k] = ck[((size_t)p * 32 + lo) * SLICE + (x - offs[lo])];
    }
  }
  // ---- h2: histogram bin-B candidates on key bits [19:8] (spread, ~1/bucket) ----
#pragma unroll
  for (int k = 0; k < CPT; ++k) {
    int x = tid + k * 256;
    if (x < Cc) {
      unsigned sv = (unsigned)(key_[k] >> 32);
      if ((int)(sv >> 20) == B) atomicAdd(&h2[(sv >> 8) & 0xFFFu], 1u);
    }
  }
  __syncthreads();
  // ---- suffix-scan h2 (desc) in place: h2[s] := # bin-B cands with sub > s ----
  {
    unsigned s = 0;
    for (int k2 = 0; k2 < 16; ++k2) s += h2[tid * 16 + k2];
    part[tid] = s;
    __syncthreads();
    if (tid == 0) {
      unsigned acc = 0;
      for (int c = 255; c >= 0; --c) { unsigned t = part[c]; part[c] = acc; acc += t; }
    }
    __syncthreads();
    unsigned run = part[tid];
    for (int k2 = 15; k2 >= 0; --k2) {
      unsigned hv = h2[tid * 16 + k2];
      h2[tid * 16 + k2] = run;
      run += hv;
    }
  }
  __syncthreads();
  // ---- snapshot bucket starts (before any cursor mutation) ----
  int st_[CPT];
#pragma unroll
  for (int k = 0; k < CPT; ++k) {
    int x = tid + k * 256;
    st_[k] = 0;
    if (x < Cc) {
      unsigned sv = (unsigned)(key_[k] >> 32);
      int b = (int)(sv >> 20);
      st_[k] = (b == B) ? (int)(H + h2[(sv >> 8) & 0xFFFu]) : (int)cur1[b];
    }
  }
  __syncthreads();
  // ---- counting-sort scatter (positions unique; regions disjoint by construction) ----
  int pos_[CPT];
#pragma unroll
  for (int k = 0; k < CPT; ++k) {
    int x = tid + k * 256;
    pos_[k] = -1;
    if (x < Cc) {
      unsigned sv = (unsigned)(key_[k] >> 32);
      int b = (int)(sv >> 20);
      unsigned pos = (b == B) ? H + atomicAdd(&h2[(sv >> 8) & 0xFFFu], 1u)
                              : atomicAdd(&cur1[b], 1u);
      if (pos < (unsigned)CAP) { skS[pos] = key_[k]; pos_[k] = (int)pos; }
    }
  }
  __syncthreads();
  // ---- exact rank = bucket_start + tiny bucket scan; then decode winners ----
#pragma unroll
  for (int k = 0; k < CPT; ++k) {
    if (pos_[k] < 0) continue;
    unsigned long long kc = key_[k];
    unsigned sv = (unsigned)(kc >> 32);
    int b = (int)(sv >> 20);
    int en = (b == B) ? (int)(H + h2[(sv >> 8) & 0xFFFu]) : (int)cur1[b];
    if (en > CAP) en = CAP;
    int st = st_[k];
    int rank = st;
    for (int j = st; j < en; ++j) rank += (skS[j] > kc) ? 1 : 0;
    if (rank >= kk) continue;
    // ---- decode (numpy-faithful, no FMA contraction) ----
    unsigned kx = 0xFFFFFFFFu - (unsigned)kc;
    int i = soff + rank;
    int slot = img * K_SEL + i;
    int f = 256 >> lvl, hw = f * f;
    const int aoffA[5] = {0, 196608, 245760, 258048, 261120};
    int a = (int)(kx % 3u); int r = (int)(kx / 3u);
    int y = r >> (8 - lvl); int xi = r & (f - 1);
    const float* dp = del.p[lvl] + (size_t)(img * 12 + a * 4) * hw + (size_t)y * f + xi;
    float d0 = dp[0], d1 = dp[hw], d2 = dp[2 * hw], d3 = dp[3 * hw];
    const float* ar = anchors + (size_t)(aoffA[lvl] + (int)kx) * 4;
    float a0 = ar[0], a1 = ar[1], a2 = ar[2], a3 = ar[3];
    float w = __fsub_rn(a2, a0), h = __fsub_rn(a3, a1);
    float cx = __fadd_rn(a0, __fmul_rn(0.5f, w));
    float cy = __fadd_rn(a1, __fmul_rn(0.5f, h));
    const float CLIP = 4.135166556742356f;     // log(1000/16)
    float dw = fminf(d2, CLIP), dh = fminf(d3, CLIP);
    float pcx = __fadd_rn(__fmul_rn(d0, w), cx);
    float pcy = __fadd_rn(__fmul_rn(d1, h), cy);
    float pw = __fmul_rn(expf(dw), w);
    float ph = __fmul_rn(expf(dh), h);
    float x1 = __fsub_rn(pcx, __fmul_rn(0.5f, pw));
    float y1 = __fsub_rn(pcy, __fmul_rn(0.5f, ph));
    float x2 = __fadd_rn(pcx, __fmul_rn(0.5f, pw));
    float y2 = __fadd_rn(pcy, __fmul_rn(0.5f, ph));
    float x1c = fminf(fmaxf(x1, 0.0f), 1024.0f);
    float y1c = fminf(fmaxf(y1, 0.0f), 1024.0f);
    float x2c = fminf(fmaxf(x2, 0.0f), 1024.0f);
    float y2c = fminf(fmaxf(y2, 0.0f), 1024.0f);
    bool valid = (__fsub_rn(x2c, x1c) >= 1e-3f) && (__fsub_rn(y2c, y1c) >= 1e-3f);
    float* bp = boxP + (size_t)slot * 4;
    bp[0] = x1c; bp[1] = y1c; bp[2] = x2c; bp[3] = y2c;
    unsigned low = 0xFFFFFFFFu - (unsigned)i;  // pos asc tie-break, unique keys
    keyP[slot] = valid ? (((unsigned long long)sv << 32) | low) : (unsigned long long)low;
  }
}

// ---------------- IoU on offset boxes, bitwise matching reference -----------------------
__device__ __forceinline__ bool iou_gt(float rx1, float ry1, float rx2, float ry2, float rar,
                                       float cx1, float cy1, float cx2, float cy2, float car) {
  float ltx = fmaxf(rx1, cx1), lty = fmaxf(ry1, cy1);
  float rbx = fminf(rx2, cx2), rby = fminf(ry2, cy2);
  float wx = fmaxf(__fsub_rn(rbx, ltx), 0.0f);
  float wy = fmaxf(__fsub_rn(rby, lty), 0.0f);
  float inter = __fmul_rn(wx, wy);
  float denom = __fadd_rn(__fsub_rn(__fadd_rn(rar, car), inter), 1e-9f);
  return __fdiv_rn(inter, denom) > 0.7f;
}

// ---- TRANSPOSED suppression mask T[i] = "which j<i suppress i", triangular-packed ------
__global__ __launch_bounds__(64) void k_lvlmask(const float* boxP, unsigned long long* T) {
  int img = blockIdx.y;
  int q = blockIdx.x;                        // 0..621 per image
  int lvl, q2;
  if (q < 544) { lvl = q / 136; q2 = q - lvl * 136; }
  else         { lvl = 4;       q2 = q - 544; }
  int kk = (lvl == 4) ? 768 : 1000;
  int nch = (kk + 63) >> 6;
  int rb = 0;
  while (q2 >= nch - rb) { q2 -= nch - rb; ++rb; }    // upper-tri (rb, cb>=rb)
  int cb = rb + q2;
  int t = threadIdx.x;
  float off = __fmul_rn((float)lvl, 1025.0f);
  const float4* b4 = (const float4*)boxP + (size_t)img * K_SEL + lvl * 1000;
  __shared__ float rx1s[64], ry1s[64], rx2s[64], ry2s[64], rars[64];
  int j = rb * 64 + t;                       // ROW box staged in LDS
  if (j < kk) {
    float4 bb = b4[j];
    float ox1 = __fadd_rn(bb.x, off), oy1 = __fadd_rn(bb.y, off);
    float ox2 = __fadd_rn(bb.z, off), oy2 = __fadd_rn(bb.w, off);
    rx1s[t] = ox1; ry1s[t] = oy1; rx2s[t] = ox2; ry2s[t] = oy2;
    rars[t] = __fmul_rn(__fsub_rn(ox2, ox1), __fsub_rn(oy2, oy1));
  }
  __syncthreads();
  int i = cb * 64 + t;                       // COLUMN box in registers
  if (i >= kk) return;
  float4 bb = b4[i];
  float cx1 = __fadd_rn(bb.x, off), cy1 = __fadd_rn(bb.y, off);
  float cx2 = __fadd_rn(bb.z, off), cy2 = __fadd_rn(bb.w, off);
  float car = __fmul_rn(__fsub_rn(cx2, cx1), __fsub_rn(cy2, cy1));
  int jmaxR = min(64, kk - rb * 64);
  int jend = (rb == cb) ? min(t, jmaxR) : jmaxR;      // diag: only rows jj < t
  unsigned long long bits = 0;
  for (int jj = 0; jj < jend; ++jj) {
    if (iou_gt(rx1s[jj], ry1s[jj], rx2s[jj], ry2s[jj], rars[jj], cx1, cy1, cx2, cy2, car))
      bits |= (1ULL << jj);
  }
  const int Pt[16] = {0, 1, 4, 7, 12, 17, 24, 31, 40, 49, 60, 71, 84, 97, 112, 127};
  int sc = (cb + 1) | 1;
  T[(size_t)(img * 5 + lvl) * TPAD + 64 * Pt[cb] + t * sc + rb] = bits;
}

// ---- per-level greedy NMS: LDS-staged T + single-wave serial chunk sweep (r4-proven) ---
__global__ __launch_bounds__(256) void k_lvlnms(const unsigned long long* keyP,
                                                const unsigned long long* Tg_,
                                                unsigned long long* keepw) {
  int p = blockIdx.x; int img = p / 5, lvl = p % 5;
  int kk = (lvl == 4) ? 768 : 1000;
  int tw = (lvl == 4) ? 5376 : TPAD;         // words used (lvl4: chunks 0..11 only)
  int tid = threadIdx.x;
  __shared__ __align__(16) unsigned long long Ts[TPAD];   // 72 KiB
  const unsigned long long* Tg = Tg_ + (size_t)p * TPAD;
  const unsigned long long* kp = keyP + (size_t)img * K_SEL + lvl * 1000;
  // wave0: prefetch validity bits for all 16 chunks (overlaps the staging loop's loads)
  unsigned vmask = 0;
  if (tid < 64) {
#pragma unroll
    for (int c = 0; c < 16; ++c) {
      int i = c * 64 + tid;
      bool v = (i < kk) && ((kp[min(i, kk - 1)] >> 32) != 0ULL);
      vmask |= v ? (1u << c) : 0u;
    }
  }
  // staging: x4-batched 16B loads (4 in flight) to hide L2/HBM latency
  {
    const ulonglong2* Tg2 = (const ulonglong2*)Tg;
    ulonglong2* Ts2 = (ulonglong2*)Ts;
    int nv = tw >> 1;
    for (int x = tid; x < nv; x += 1024) {
      int x1i = x + 256, x2i = x + 512, x3i = x + 768;
      ulonglong2 a0 = Tg2[x], a1 = {}, a2 = {}, a3 = {};
      if (x1i < nv) a1 = Tg2[x1i];
      if (x2i < nv) a2 = Tg2[x2i];
      if (x3i < nv) a3 = Tg2[x3i];
      Ts2[x] = a0;
      if (x1i < nv) Ts2[x1i] = a1;
      if (x2i < nv) Ts2[x2i] = a2;
      if (x3i < nv) Ts2[x3i] = a3;
    }
  }
  __syncthreads();
  if (tid >= 64) return;                     // waves 1-3 done (no further barriers)
  int t = tid;
  const int Pt[16] = {0, 1, 4, 7, 12, 17, 24, 31, 40, 49, 60, 71, 84, 97, 112, 127};
  unsigned long long kw[16];
#pragma unroll
  for (int w = 0; w < 16; ++w) kw[w] = 0ULL;
#pragma unroll
  for (int c = 0; c < 16; ++c) {
    if (c * 64 < kk) {
      int base = 64 * Pt[c] + t * ((c + 1) | 1);
      unsigned long long tv[16];
#pragma unroll
      for (int w = 0; w < 16; ++w) tv[w] = Ts[base + w]; // batch reads; w>c garbage, masked
      unsigned long long a = 0;
#pragma unroll
      for (int w = 0; w < 16; ++w) a |= tv[w] & kw[w];   // kw[w]=0 for w>=c
      unsigned long long colT = tv[c];                   // diag word: suppressors j<t in chunk
      bool alive = ((vmask >> c) & 1u) && (a == 0ULL);
      unsigned long long keepm = 0ULL;
      unsigned long long actm = __ballot(alive);
      while (actm) {
        bool cank = alive && ((colT & actm) == 0ULL);    // no alive suppressor below t
        unsigned long long newk = __ballot(cank);
        keepm |= newk;
        alive = alive && !cank && ((colT & newk) == 0ULL);
        actm = __ballot(alive);
      }
      kw[c] = keepm;                                     // static index (unrolled)
    }
  }
  if (t == 0) {
#pragma unroll
    for (int c = 0; c < 16; ++c) keepw[(size_t)p * 16 + c] = kw[c];  // uniform ballot values
  }
}

// ---- merge: 40 blocks = (img,lvl); each compacts all levels (coalesced) but ranks only
// ---- its own level's kept entries (4 interleaved binary searches, short LDS chains) ----
__global__ __launch_bounds__(256) void k_merge(const unsigned long long* keyP, const float* boxP,
                                               const unsigned long long* keepw, float* out) {
  int p = blockIdx.x; int img = p / 5, lvl = p % 5;
  int tid = threadIdx.x;
  __shared__ unsigned long long lkey[5000];   // level l at l*1000: compacted kept keys (desc)
  __shared__ int lpos[5000];                  // original within-image slot
  __shared__ int wp[5][17];                   // per-level word-prefix popcounts
  __shared__ unsigned long long kwS[80];
  for (int x = tid; x < 80; x += 256) {
    kwS[x] = keepw[(size_t)img * 80 + x];     // all 16 words written by k_lvlnms
  }
  __syncthreads();
  if (tid < 5) {
    int acc = 0;
    for (int w = 0; w < 16; ++w) { wp[tid][w] = acc; acc += (int)__popcll(kwS[tid * 16 + w]); }
    wp[tid][16] = acc;
  }
  __syncthreads();
  const unsigned long long* kp = keyP + (size_t)img * K_SEL;
  for (int i = tid; i < K_SEL; i += 256) {
    int l = (i < 4000) ? i / 1000 : 4;
    int li = i - l * 1000;
    unsigned long long wmask = kwS[l * 16 + (li >> 6)];
    if ((wmask >> (li & 63)) & 1ULL) {
      int j = wp[l][li >> 6] + (int)__popcll(wmask & ((1ULL << (li & 63)) - 1ULL));
      lkey[l * 1000 + j] = kp[i];
      lpos[l * 1000 + j] = i;
    }
  }
  __syncthreads();
  const float4* b4 = (const float4*)boxP + (size_t)img * K_SEL;
  float4* out4 = (float4*)out + (size_t)img * 1000;
  int kn = wp[lvl][16];
  for (int j = tid; j < kn; j += 256) {
    unsigned long long key = lkey[lvl * 1000 + j];
    int grank = j;
#pragma unroll
    for (int l2 = 0; l2 < 5; ++l2) {
      if (l2 == lvl) continue;
      int lo = 0, hi = wp[l2][16];
      const unsigned long long* a = &lkey[l2 * 1000];
      while (lo < hi) { int mid = (lo + hi) >> 1; if (a[mid] > key) lo = mid + 1; else hi = mid; }
      grank += lo;                            // count of keys > key in level l2
    }
    if (grank < 1000) out4[grank] = b4[lpos[lvl * 1000 + j]];
  }
  if (lvl == 0) {                             // pad region [KT,1000) has no grank: disjoint
    int KT = wp[0][16] + wp[1][16] + wp[2][16] + wp[3][16] + wp[4][16];
    for (int s = min(KT, 1000) + tid; s < 1000; s += 256)
      out4[s] = make_float4(0.f, 0.f, 0.f, 0.f);          // zero-pad tail
  }
}

extern "C" void kernel_launch(void* const* d_in, const int* in_sizes, int n_in,
                              void* d_out, int out_size, void* d_ws, size_t ws_size,
                              hipStream_t stream) {
  (void)in_sizes; (void)n_in;
  // setup_inputs() dict order is INTERLEAVED: obj_l0, delta_l0, obj_l1, delta_l1, ..., anchors
  P5 obj, del;
  for (int i = 0; i < 5; ++i) {
    obj.p[i] = (const float*)d_in[2 * i];
    del.p[i] = (const float*)d_in[2 * i + 1];
  }
  const float* anchors = (const float*)d_in[10];
  float* out = (float*)d_out;
  char* ws = (char*)d_ws;

  // ws layout (bytes) — nothing needs zero-init
  unsigned* cntB              = (unsigned*)(ws + 0);                   // 5120
  int* Bthr                   = (int*)(ws + 5120);                     // 160 -> 5280
  unsigned* cumA              = (unsigned*)(ws + 5376);                // 40*4096*4 = 655360 -> 660736
  unsigned long long* candK   = (unsigned long long*)(ws + 663552);    // 5242880 -> 5906432
  float* boxP                 = (float*)(ws + 5906432);                // 610304 -> 6516736
  unsigned long long* keyP    = (unsigned long long*)(ws + 6516736);   // 305152 -> 6821888
  unsigned long long* keepw   = (unsigned long long*)(ws + 6821888);   // 5120 -> 6827008
  unsigned long long* T       = (unsigned long long*)(ws + 6827008);   // 2949120 -> 9776128
  unsigned* phist             = (unsigned*)(ws + 6827008);             // overlay on T (dead before k_lvlmask): 5242880 -> 12069888
  const size_t NEED = 12069888ULL;
  if (ws_size < NEED) { hipMemsetAsync(d_out, 0, (size_t)out_size * 4, stream); return; }

  k_hist    <<<dim3(8, 40), 256, 0, stream>>>(obj, phist);
  k_thresh  <<<40, 256, 0, stream>>>(phist, Bthr, cumA);
  k_gather  <<<dim3(32, 40), 256, 0, stream>>>(obj, Bthr, cntB, candK);
  k_seldec  <<<40, 256, 0, stream>>>(del, anchors, Bthr, cumA, cntB, candK, boxP, keyP);
  k_lvlmask <<<dim3(622, 8), 64, 0, stream>>>(boxP, T);
  k_lvlnms  <<<40, 256, 0, stream>>>(keyP, T, keepw);
  k_merge   <<<40, 256, 0, stream>>>(keyP, boxP, keepw, out);
}

// Round 12
// 218.079 us; speedup vs baseline: 1.2543x; 1.2543x over previous
//
#include <hip/hip_runtime.h>
#include <cstdint>

#define K_SEL 4768
#define NBIN 4096
#define BUFCAP 512
#define SLICE 512
#define CAPR 4608    // raw candidate capacity (CPT*256)
#define CPT 18
#define CAP2 2048    // survivor capacity after 24-bit refine (typ ~kk+5)
#define TPAD 9216    // padded-triangular T words per (img,lvl)

struct P5 { const float* p[5]; };

__device__ __forceinline__ unsigned fsortkey(float f) {
  unsigned b = __float_as_uint(f);
  return (b & 0x80000000u) ? ~b : (b | 0x80000000u);
}

// ------- histogram of sortable-logit top-12 bits per (img,lvl): per-block partials ------
__global__ __launch_bounds__(256) void k_hist(P5 obj, unsigned* phist) {
  int p = blockIdx.y; int img = p / 5, lvl = p % 5;
  int f = 256 >> lvl; int n = 3 * f * f;
  __shared__ unsigned lh[NBIN];
  for (int b = threadIdx.x; b < NBIN; b += 256) lh[b] = 0;
  __syncthreads();
  const float4* src4 = (const float4*)(obj.p[lvl] + (size_t)img * n);
  int n4 = n >> 2;
  int chunk = (n4 + gridDim.x - 1) / gridDim.x;
  int e0 = blockIdx.x * chunk, e1 = min(n4, e0 + chunk);
  for (int e = e0 + threadIdx.x; e < e1; e += 256) {
    float4 v = src4[e];
    atomicAdd(&lh[fsortkey(v.x) >> 20], 1u);
    atomicAdd(&lh[fsortkey(v.y) >> 20], 1u);
    atomicAdd(&lh[fsortkey(v.z) >> 20], 1u);
    atomicAdd(&lh[fsortkey(v.w) >> 20], 1u);
  }
  __syncthreads();
  unsigned* dst = phist + ((size_t)(p * 8 + blockIdx.x)) * NBIN;
  for (int b = threadIdx.x; b < NBIN; b += 256) dst[b] = lh[b];   // unconditional: no pre-zero
}

// ------- sum partials, find threshold bin B; also H = #elems in bins > B ---------------
__global__ __launch_bounds__(256) void k_thresh(const unsigned* phist, int* Bthr,
                                                unsigned* Hthr) {
  int p = blockIdx.x; int lvl = p % 5;
  unsigned kk = (lvl == 4) ? 768u : 1000u;
  __shared__ unsigned hsum[NBIN];
  __shared__ unsigned csum[256];
  int c = threadIdx.x;
  unsigned tot[16];
#pragma unroll
  for (int k = 0; k < 16; ++k) tot[k] = 0;
  for (int g = 0; g < 8; ++g) {
    const unsigned* hp = phist + ((size_t)(p * 8 + g)) * NBIN + c * 16;
#pragma unroll
    for (int k = 0; k < 16; ++k) tot[k] += hp[k];
  }
  unsigned s = 0;
#pragma unroll
  for (int k = 0; k < 16; ++k) { hsum[c * 16 + k] = tot[k]; s += tot[k]; }
  csum[c] = s;
  __syncthreads();
  if (c == 0) {
    unsigned acc = 0, H = 0; int B = 0;
    for (int cc = 255; cc >= 0; --cc) {
      if (acc + csum[cc] >= kk) {
        for (int b = 15; b >= 0; --b) {
          H = acc;                             // count in bins strictly above current bin
          acc += hsum[cc * 16 + b];
          if (acc >= kk) { B = cc * 16 + b; break; }
        }
        break;
      }
      acc += csum[cc];
    }
    Bthr[p] = B;
    Hthr[p] = H;
  }
}

// ------- gather: 32 blocks per p; per-block 512-key slice, plain-store count ------------
__global__ __launch_bounds__(256) void k_gather(P5 obj, const int* Bthr,
                                                unsigned* cntB, unsigned long long* ck) {
  int p = blockIdx.y; int img = p / 5, lvl = p % 5;
  int f = 256 >> lvl; int hw = f * f; int n = 3 * hw;
  int B = Bthr[p];
  int tid = threadIdx.x;
  int lane = tid & 63, wv = tid >> 6;
  int shift = 2 * (8 - lvl);
  const float4* src4 = (const float4*)(obj.p[lvl] + (size_t)img * n);
  int n4 = n >> 2;
  int chunk = (n4 + 31) >> 5;                  // gridDim.x == 32
  int e0 = blockIdx.x * chunk, e1 = min(n4, e0 + chunk);
  __shared__ unsigned long long buf[4][BUFCAP];
  __shared__ unsigned wTot[4];
  unsigned wc = 0;                             // wave-uniform running count
  for (int e = e0 + tid; e < e1; e += 256) {
    float4 v = src4[e];
    float vv[4] = {v.x, v.y, v.z, v.w};
#pragma unroll
    for (int j = 0; j < 4; ++j) {
      unsigned sv = fsortkey(vv[j]);
      bool pass = (int)(sv >> 20) >= B;
      unsigned long long m = __ballot(pass);
      if (m) {
        if (pass) {
          unsigned pos = wc + (unsigned)__popcll(m & ((1ULL << lane) - 1ULL));
          int ee = e * 4 + j;
          int a = ee >> shift;                 // ee / hw
          int r = ee & (hw - 1);               // ee % hw
          unsigned kidx = (unsigned)(r * 3 + a); // reference flatten order (y*W+x)*A + a
          unsigned long long key = ((unsigned long long)sv << 32) | (0xFFFFFFFFu - kidx);
          if (pos < BUFCAP) buf[wv][pos] = key; // overflow (pathological only): drop
        }
        wc += (unsigned)__popcll(m);
      }
    }
  }
  if (lane == 0) wTot[wv] = min(wc, (unsigned)BUFCAP);
  __syncthreads();
  unsigned myOff = 0;
  for (int x = 0; x < wv; ++x) myOff += wTot[x];
  unsigned tot4 = wTot[0] + wTot[1] + wTot[2] + wTot[3];
  unsigned long long* dst = ck + ((size_t)p * 32 + blockIdx.x) * SLICE;
  for (unsigned j = lane; j < wTot[wv]; j += 64) {
    unsigned gp = myOff + j;
    if (gp < SLICE) dst[gp] = buf[wv][j];      // coalesced slice flush, no atomics
  }
  if (tid == 0) cntB[p * 32 + blockIdx.x] = min(tot4, (unsigned)SLICE);
}

// ------- refine: sub-histogram bin-B ties on key bits [19:8] -> 24-bit threshold B2 -----
// Survivor set shrinks from ~4300 (12-bit ties) to ~kk+5 (24-bit ties): seldec's rank
// scan and decode-prefetch population drop ~4x. 40 blocks, reads ~34KB/p (L2-warm).
__global__ __launch_bounds__(256) void k_thresh2(const int* Bthr, const unsigned* Hthr,
                                                 const unsigned* cntB,
                                                 const unsigned long long* ck,
                                                 int* B2thr, unsigned* Cc2g) {
  int p = blockIdx.x; int lvl = p % 5;
  unsigned kk = (lvl == 4) ? 768u : 1000u;
  int B1 = Bthr[p];
  unsigned H = Hthr[p];
  unsigned kk2 = kk - H;                       // >= 1 by construction of B1
  int tid = threadIdx.x;
  __shared__ unsigned h2[NBIN];
  __shared__ unsigned csum[256];
  __shared__ unsigned offs[33];
  for (int x = tid; x < NBIN; x += 256) h2[x] = 0;
  if (tid < 32) {                              // wave prefix of slice counts
    unsigned v = cntB[p * 32 + tid];
#pragma unroll
    for (int d = 1; d < 32; d <<= 1) {
      unsigned o = __shfl(v, tid - d);
      if (tid >= d) v += o;
    }
    offs[tid + 1] = v;
    if (tid == 0) offs[0] = 0;
  }
  __syncthreads();
  int Cc = min((int)offs[32], CAPR);
  for (int x = tid; x < Cc; x += 256) {
    int lo = 0;
#pragma unroll
    for (int d = 16; d; d >>= 1)
      if (offs[lo + d] <= (unsigned)x) lo += d;
    unsigned long long key = ck[((size_t)p * 32 + lo) * SLICE + (x - offs[lo])];
    unsigned sv = (unsigned)(key >> 32);
    if ((int)(sv >> 20) == B1) atomicAdd(&h2[(sv >> 8) & 0xFFFu], 1u);
  }
  __syncthreads();
  unsigned s = 0;
  for (int k = 0; k < 16; ++k) s += h2[tid * 16 + k];
  csum[tid] = s;
  __syncthreads();
  if (tid == 0) {
    unsigned acc = 0; int B2 = 0;
    for (int cc = 255; cc >= 0; --cc) {
      if (acc + csum[cc] >= kk2) {
        for (int b = 15; b >= 0; --b) {
          acc += h2[cc * 16 + b];
          if (acc >= kk2) { B2 = cc * 16 + b; break; }
        }
        break;
      }
      acc += csum[cc];
    }
    B2thr[p] = B2;
    Cc2g[p] = H + acc;                         // survivors (acc = #sub >= B2)
  }
}

// ------- select+decode v3: filter to 24-bit survivors, tiny scan, full parallelism ------
// Each block (8 per p) stages+filters ALL candidates in registers, builds the SAME
// deterministic compaction (shfl prefix in fixed (tid,k) order), then ranks its 256
// survivors by a ~Cc2-iteration scan (was 4096) with r9's prefetch-then-rank decode.
__global__ __launch_bounds__(256) void k_seldec(P5 del, const float* anchors,
                                                const int* Bthr, const int* B2thr,
                                                const unsigned* Cc2g,
                                                const unsigned* cntB,
                                                const unsigned long long* ck,
                                                float* boxP, unsigned long long* keyP) {
  int p = blockIdx.y; int img = p / 5, lvl = p % 5;
  int kk = (lvl == 4) ? 768 : 1000;
  int soff = lvl * 1000;
  int tid = threadIdx.x;
  int lane = tid & 63, wv = tid >> 6;
  unsigned Cc2 = min(Cc2g[p], (unsigned)CAP2);
  if ((unsigned)(blockIdx.x * 256) >= Cc2) return;
  __shared__ unsigned long long skc[CAP2];     // 16 KiB survivors
  __shared__ unsigned offs[33];
  __shared__ unsigned wsum[4];
  if (tid < 32) {                              // wave prefix of slice counts
    unsigned v = cntB[p * 32 + tid];
#pragma unroll
    for (int d = 1; d < 32; d <<= 1) {
      unsigned o = __shfl(v, tid - d);
      if (tid >= d) v += o;
    }
    offs[tid + 1] = v;
    if (tid == 0) offs[0] = 0;
  }
  __syncthreads();
  int B1 = Bthr[p], B2 = B2thr[p];
  int Cc = min((int)offs[32], CAPR);
  // ---- stage + filter my strided candidates (fixed (tid,k) order in every block) ----
  unsigned long long key_[CPT];
  bool sur_[CPT];
  unsigned myc = 0;
#pragma unroll
  for (int k = 0; k < CPT; ++k) {
    int x = tid + k * 256;
    key_[k] = 0ULL; sur_[k] = false;
    if (x < Cc) {
      int lo = 0;
#pragma unroll
      for (int d = 16; d; d >>= 1)
        if (offs[lo + d] <= (unsigned)x) lo += d;
      key_[k] = ck[((size_t)p * 32 + lo) * SLICE + (x - offs[lo])];
      unsigned sv = (unsigned)(key_[k] >> 32);
      int b = (int)(sv >> 20);
      sur_[k] = (b > B1) || (b == B1 && (int)((sv >> 8) & 0xFFFu) >= B2);
      myc += sur_[k] ? 1u : 0u;
    }
  }
  // ---- deterministic block prefix of per-thread survivor counts ----
  unsigned v = myc;
#pragma unroll
  for (int d = 1; d < 64; d <<= 1) {
    unsigned o = __shfl(v, lane - d);
    if (lane >= d) v += o;
  }
  if (lane == 63) wsum[wv] = v;
  __syncthreads();
  unsigned base = 0;
  for (int x = 0; x < wv; ++x) base += wsum[x];
  unsigned pos = base + v - myc;               // exclusive prefix in (tid) order
  unsigned Ccc = wsum[0] + wsum[1] + wsum[2] + wsum[3];
#pragma unroll
  for (int k = 0; k < CPT; ++k) {
    if (sur_[k]) { if (pos < (unsigned)CAP2) skc[pos] = key_[k]; ++pos; }
  }
  __syncthreads();
  int Cs = min((int)Ccc, CAP2);
  int c = blockIdx.x * 256 + tid;
  if (c >= Cs) return;
  unsigned long long kc = skc[c];
  // ---- prefetch decode inputs (scattered, cold HBM) before the rank scan ----
  unsigned kx = 0xFFFFFFFFu - (unsigned)kc;
  unsigned sv = (unsigned)(kc >> 32);
  int f = 256 >> lvl, hw = f * f;
  const int aoffA[5] = {0, 196608, 245760, 258048, 261120};
  int a = (int)(kx % 3u); int r = (int)(kx / 3u);
  int y = r >> (8 - lvl); int xi = r & (f - 1);
  const float* dp = del.p[lvl] + (size_t)(img * 12 + a * 4) * hw + (size_t)y * f + xi;
  float d0 = dp[0], d1 = dp[hw], d2 = dp[2 * hw], d3 = dp[3 * hw];
  const float* ar = anchors + (size_t)(aoffA[lvl] + (int)kx) * 4;
  float a0 = ar[0], a1 = ar[1], a2 = ar[2], a3 = ar[3];
  // ---- rank scan over survivors only (~kk+ties) ----
  int rank = 0;
#pragma unroll 8
  for (int j = 0; j < Cs; ++j) rank += (skc[j] > kc) ? 1 : 0;
  if (rank >= kk) return;
  // ---- decode (numpy-faithful, no FMA contraction) ----
  int i = soff + rank;
  int slot = img * K_SEL + i;
  float w = __fsub_rn(a2, a0), h = __fsub_rn(a3, a1);
  float cx = __fadd_rn(a0, __fmul_rn(0.5f, w));
  float cy = __fadd_rn(a1, __fmul_rn(0.5f, h));
  const float CLIP = 4.135166556742356f;     // log(1000/16)
  float dw = fminf(d2, CLIP), dh = fminf(d3, CLIP);
  float pcx = __fadd_rn(__fmul_rn(d0, w), cx);
  float pcy = __fadd_rn(__fmul_rn(d1, h), cy);
  float pw = __fmul_rn(expf(dw), w);
  float ph = __fmul_rn(expf(dh), h);
  float x1 = __fsub_rn(pcx, __fmul_rn(0.5f, pw));
  float y1 = __fsub_rn(pcy, __fmul_rn(0.5f, ph));
  float x2 = __fadd_rn(pcx, __fmul_rn(0.5f, pw));
  float y2 = __fadd_rn(pcy, __fmul_rn(0.5f, ph));
  float x1c = fminf(fmaxf(x1, 0.0f), 1024.0f);
  float y1c = fminf(fmaxf(y1, 0.0f), 1024.0f);
  float x2c = fminf(fmaxf(x2, 0.0f), 1024.0f);
  float y2c = fminf(fmaxf(y2, 0.0f), 1024.0f);
  bool valid = (__fsub_rn(x2c, x1c) >= 1e-3f) && (__fsub_rn(y2c, y1c) >= 1e-3f);
  float* bp = boxP + (size_t)slot * 4;
  bp[0] = x1c; bp[1] = y1c; bp[2] = x2c; bp[3] = y2c;
  unsigned low = 0xFFFFFFFFu - (unsigned)i;    // pos asc tie-break, unique keys
  keyP[slot] = valid ? (((unsigned long long)sv << 32) | low) : (unsigned long long)low;
}

// ---------------- IoU on offset boxes, bitwise matching reference -----------------------
__device__ __forceinline__ bool iou_gt(float rx1, float ry1, float rx2, float ry2, float rar,
                                       float cx1, float cy1, float cx2, float cy2, float car) {
  float ltx = fmaxf(rx1, cx1), lty = fmaxf(ry1, cy1);
  float rbx = fminf(rx2, cx2), rby = fminf(ry2, cy2);
  float wx = fmaxf(__fsub_rn(rbx, ltx), 0.0f);
  float wy = fmaxf(__fsub_rn(rby, lty), 0.0f);
  float inter = __fmul_rn(wx, wy);
  float denom = __fadd_rn(__fsub_rn(__fadd_rn(rar, car), inter), 1e-9f);
  return __fdiv_rn(inter, denom) > 0.7f;
}

// ---- TRANSPOSED suppression mask T[i] = "which j<i suppress i", triangular-packed ------
__global__ __launch_bounds__(64) void k_lvlmask(const float* boxP, unsigned long long* T) {
  int img = blockIdx.y;
  int q = blockIdx.x;                        // 0..621 per image
  int lvl, q2;
  if (q < 544) { lvl = q / 136; q2 = q - lvl * 136; }
  else         { lvl = 4;       q2 = q - 544; }
  int kk = (lvl == 4) ? 768 : 1000;
  int nch = (kk + 63) >> 6;
  int rb = 0;
  while (q2 >= nch - rb) { q2 -= nch - rb; ++rb; }    // upper-tri (rb, cb>=rb)
  int cb = rb + q2;
  int t = threadIdx.x;
  float off = __fmul_rn((float)lvl, 1025.0f);
  const float4* b4 = (const float4*)boxP + (size_t)img * K_SEL + lvl * 1000;
  __shared__ float rx1s[64], ry1s[64], rx2s[64], ry2s[64], rars[64];
  int j = rb * 64 + t;                       // ROW box staged in LDS
  if (j < kk) {
    float4 bb = b4[j];
    float ox1 = __fadd_rn(bb.x, off), oy1 = __fadd_rn(bb.y, off);
    float ox2 = __fadd_rn(bb.z, off), oy2 = __fadd_rn(bb.w, off);
    rx1s[t] = ox1; ry1s[t] = oy1; rx2s[t] = ox2; ry2s[t] = oy2;
    rars[t] = __fmul_rn(__fsub_rn(ox2, ox1), __fsub_rn(oy2, oy1));
  }
  __syncthreads();
  int i = cb * 64 + t;                       // COLUMN box in registers
  if (i >= kk) return;
  float4 bb = b4[i];
  float cx1 = __fadd_rn(bb.x, off), cy1 = __fadd_rn(bb.y, off);
  float cx2 = __fadd_rn(bb.z, off), cy2 = __fadd_rn(bb.w, off);
  float car = __fmul_rn(__fsub_rn(cx2, cx1), __fsub_rn(cy2, cy1));
  int jmaxR = min(64, kk - rb * 64);
  int jend = (rb == cb) ? min(t, jmaxR) : jmaxR;      // diag: only rows jj < t
  unsigned long long bits = 0;
  for (int jj = 0; jj < jend; ++jj) {
    if (iou_gt(rx1s[jj], ry1s[jj], rx2s[jj], ry2s[jj], rars[jj], cx1, cy1, cx2, cy2, car))
      bits |= (1ULL << jj);
  }
  const int Pt[16] = {0, 1, 4, 7, 12, 17, 24, 31, 40, 49, 60, 71, 84, 97, 112, 127};
  int sc = (cb + 1) | 1;
  T[(size_t)(img * 5 + lvl) * TPAD + 64 * Pt[cb] + t * sc + rb] = bits;
}

// ---- per-level greedy NMS: LDS-staged T + single-wave serial chunk sweep (r4-proven) ---
__global__ __launch_bounds__(256) void k_lvlnms(const unsigned long long* keyP,
                                                const unsigned long long* Tg_,
                                                unsigned long long* keepw) {
  int p = blockIdx.x; int img = p / 5, lvl = p % 5;
  int kk = (lvl == 4) ? 768 : 1000;
  int tw = (lvl == 4) ? 5376 : TPAD;         // words used (lvl4: chunks 0..11 only)
  int tid = threadIdx.x;
  __shared__ __align__(16) unsigned long long Ts[TPAD];   // 72 KiB
  const unsigned long long* Tg = Tg_ + (size_t)p * TPAD;
  const unsigned long long* kp = keyP + (size_t)img * K_SEL + lvl * 1000;
  // wave0: prefetch validity bits for all 16 chunks (overlaps the staging loop's loads)
  unsigned vmask = 0;
  if (tid < 64) {
#pragma unroll
    for (int c = 0; c < 16; ++c) {
      int i = c * 64 + tid;
      bool v = (i < kk) && ((kp[min(i, kk - 1)] >> 32) != 0ULL);
      vmask |= v ? (1u << c) : 0u;
    }
  }
  // staging: x4-batched 16B loads (4 in flight) to hide L2/HBM latency
  {
    const ulonglong2* Tg2 = (const ulonglong2*)Tg;
    ulonglong2* Ts2 = (ulonglong2*)Ts;
    int nv = tw >> 1;
    for (int x = tid; x < nv; x += 1024) {
      int x1i = x + 256, x2i = x + 512, x3i = x + 768;
      ulonglong2 a0 = Tg2[x], a1 = {}, a2 = {}, a3 = {};
      if (x1i < nv) a1 = Tg2[x1i];
      if (x2i < nv) a2 = Tg2[x2i];
      if (x3i < nv) a3 = Tg2[x3i];
      Ts2[x] = a0;
      if (x1i < nv) Ts2[x1i] = a1;
      if (x2i < nv) Ts2[x2i] = a2;
      if (x3i < nv) Ts2[x3i] = a3;
    }
  }
  __syncthreads();
  if (tid >= 64) return;                     // waves 1-3 done (no further barriers)
  int t = tid;
  const int Pt[16] = {0, 1, 4, 7, 12, 17, 24, 31, 40, 49, 60, 71, 84, 97, 112, 127};
  unsigned long long kw[16];
#pragma unroll
  for (int w = 0; w < 16; ++w) kw[w] = 0ULL;
#pragma unroll
  for (int c = 0; c < 16; ++c) {
    if (c * 64 < kk) {
      int base = 64 * Pt[c] + t * ((c + 1) | 1);
      unsigned long long tv[16];
#pragma unroll
      for (int w = 0; w < 16; ++w) tv[w] = Ts[base + w]; // batch reads; w>c garbage, masked
      unsigned long long a = 0;
#pragma unroll
      for (int w = 0; w < 16; ++w) a |= tv[w] & kw[w];   // kw[w]=0 for w>=c
      unsigned long long colT = tv[c];                   // diag word: suppressors j<t in chunk
      bool alive = ((vmask >> c) & 1u) && (a == 0ULL);
      unsigned long long keepm = 0ULL;
      unsigned long long actm = __ballot(alive);
      while (actm) {
        bool cank = alive && ((colT & actm) == 0ULL);    // no alive suppressor below t
        unsigned long long newk = __ballot(cank);
        keepm |= newk;
        alive = alive && !cank && ((colT & newk) == 0ULL);
        actm = __ballot(alive);
      }
      kw[c] = keepm;                                     // static index (unrolled)
    }
  }
  if (t == 0) {
#pragma unroll
    for (int c = 0; c < 16; ++c) keepw[(size_t)p * 16 + c] = kw[c];  // uniform ballot values
  }
}

// ---- merge: 40 blocks = (img,lvl); each compacts all levels (coalesced) but ranks only
// ---- its own level's kept entries (4 interleaved binary searches, short LDS chains) ----
__global__ __launch_bounds__(256) void k_merge(const unsigned long long* keyP, const float* boxP,
                                               const unsigned long long* keepw, float* out) {
  int p = blockIdx.x; int img = p / 5, lvl = p % 5;
  int tid = threadIdx.x;
  __shared__ unsigned long long lkey[5000];   // level l at l*1000: compacted kept keys (desc)
  __shared__ int lpos[5000];                  // original within-image slot
  __shared__ int wp[5][17];                   // per-level word-prefix popcounts
  __shared__ unsigned long long kwS[80];
  for (int x = tid; x < 80; x += 256) {
    kwS[x] = keepw[(size_t)img * 80 + x];     // all 16 words written by k_lvlnms
  }
  __syncthreads();
  if (tid < 5) {
    int acc = 0;
    for (int w = 0; w < 16; ++w) { wp[tid][w] = acc; acc += (int)__popcll(kwS[tid * 16 + w]); }
    wp[tid][16] = acc;
  }
  __syncthreads();
  const unsigned long long* kp = keyP + (size_t)img * K_SEL;
  for (int i = tid; i < K_SEL; i += 256) {
    int l = (i < 4000) ? i / 1000 : 4;
    int li = i - l * 1000;
    unsigned long long wmask = kwS[l * 16 + (li >> 6)];
    if ((wmask >> (li & 63)) & 1ULL) {
      int j = wp[l][li >> 6] + (int)__popcll(wmask & ((1ULL << (li & 63)) - 1ULL));
      lkey[l * 1000 + j] = kp[i];
      lpos[l * 1000 + j] = i;
    }
  }
  __syncthreads();
  const float4* b4 = (const float4*)boxP + (size_t)img * K_SEL;
  float4* out4 = (float4*)out + (size_t)img * 1000;
  int kn = wp[lvl][16];
  for (int j = tid; j < kn; j += 256) {
    unsigned long long key = lkey[lvl * 1000 + j];
    int grank = j;
#pragma unroll
    for (int l2 = 0; l2 < 5; ++l2) {
      if (l2 == lvl) continue;
      int lo = 0, hi = wp[l2][16];
      const unsigned long long* a = &lkey[l2 * 1000];
      while (lo < hi) { int mid = (lo + hi) >> 1; if (a[mid] > key) lo = mid + 1; else hi = mid; }
      grank += lo;                            // count of keys > key in level l2
    }
    if (grank < 1000) out4[grank] = b4[lpos[lvl * 1000 + j]];
  }
  if (lvl == 0) {                             // pad region [KT,1000) has no grank: disjoint
    int KT = wp[0][16] + wp[1][16] + wp[2][16] + wp[3][16] + wp[4][16];
    for (int s = min(KT, 1000) + tid; s < 1000; s += 256)
      out4[s] = make_float4(0.f, 0.f, 0.f, 0.f);          // zero-pad tail
  }
}

extern "C" void kernel_launch(void* const* d_in, const int* in_sizes, int n_in,
                              void* d_out, int out_size, void* d_ws, size_t ws_size,
                              hipStream_t stream) {
  (void)in_sizes; (void)n_in;
  // setup_inputs() dict order is INTERLEAVED: obj_l0, delta_l0, obj_l1, delta_l1, ..., anchors
  P5 obj, del;
  for (int i = 0; i < 5; ++i) {
    obj.p[i] = (const float*)d_in[2 * i];
    del.p[i] = (const float*)d_in[2 * i + 1];
  }
  const float* anchors = (const float*)d_in[10];
  float* out = (float*)d_out;
  char* ws = (char*)d_ws;

  // ws layout (bytes) — nothing needs zero-init
  unsigned* cntB              = (unsigned*)(ws + 0);                   // 5120
  int* Bthr                   = (int*)(ws + 5120);                     // 160 -> 5280
  unsigned* Hthr              = (unsigned*)(ws + 5280);                // 160 -> 5440
  int* B2thr                  = (int*)(ws + 5440);                     // 160 -> 5600
  unsigned* Cc2g              = (unsigned*)(ws + 5600);                // 160 -> 5760
  unsigned long long* candK   = (unsigned long long*)(ws + 8192);      // 5242880 -> 5251072
  float* boxP                 = (float*)(ws + 5548544);                // 610304 -> 6158848
  unsigned long long* keyP    = (unsigned long long*)(ws + 6158848);   // 305152 -> 6464000
  unsigned long long* keepw   = (unsigned long long*)(ws + 6464000);   // 5120 -> 6469120
  unsigned long long* T       = (unsigned long long*)(ws + 6469120);   // 2949120 -> 9418240
  unsigned* phist             = (unsigned*)(ws + 6469120);             // overlay on T (dead before k_lvlmask): 5242880 -> 11712000
  const size_t NEED = 11712000ULL;
  if (ws_size < NEED) { hipMemsetAsync(d_out, 0, (size_t)out_size * 4, stream); return; }

  k_hist    <<<dim3(8, 40), 256, 0, stream>>>(obj, phist);
  k_thresh  <<<40, 256, 0, stream>>>(phist, Bthr, Hthr);
  k_gather  <<<dim3(32, 40), 256, 0, stream>>>(obj, Bthr, cntB, candK);
  k_thresh2 <<<40, 256, 0, stream>>>(Bthr, Hthr, cntB, candK, B2thr, Cc2g);
  k_seldec  <<<dim3(8, 40), 256, 0, stream>>>(del, anchors, Bthr, B2thr, Cc2g, cntB,
                                              candK, boxP, keyP);
  k_lvlmask <<<dim3(622, 8), 64, 0, stream>>>(boxP, T);
  k_lvlnms  <<<40, 256, 0, stream>>>(keyP, T, keepw);
  k_merge   <<<40, 256, 0, stream>>>(keyP, boxP, keepw, out);
}

// Round 13
// 201.278 us; speedup vs baseline: 1.3589x; 1.0835x over previous
//
#include <hip/hip_runtime.h>
#include <cstdint>

#define K_SEL 4768
#define NBIN 4096
#define BUFCAP 512
#define SLICE 512
#define TPAD 9216   // padded-triangular T words per (img,lvl): 64 * sum((c+1)|1, c=0..15)

struct P5 { const float* p[5]; };

__device__ __forceinline__ unsigned fsortkey(float f) {
  unsigned b = __float_as_uint(f);
  return (b & 0x80000000u) ? ~b : (b | 0x80000000u);
}

// ------- histogram of sortable-logit top-12 bits per (img,lvl): per-block partials ------
__global__ __launch_bounds__(256) void k_hist(P5 obj, unsigned* phist) {
  int p = blockIdx.y; int img = p / 5, lvl = p % 5;
  int f = 256 >> lvl; int n = 3 * f * f;
  __shared__ unsigned lh[NBIN];
  for (int b = threadIdx.x; b < NBIN; b += 256) lh[b] = 0;
  __syncthreads();
  const float4* src4 = (const float4*)(obj.p[lvl] + (size_t)img * n);
  int n4 = n >> 2;
  int chunk = (n4 + gridDim.x - 1) / gridDim.x;
  int e0 = blockIdx.x * chunk, e1 = min(n4, e0 + chunk);
  for (int e = e0 + threadIdx.x; e < e1; e += 256) {
    float4 v = src4[e];
    atomicAdd(&lh[fsortkey(v.x) >> 20], 1u);
    atomicAdd(&lh[fsortkey(v.y) >> 20], 1u);
    atomicAdd(&lh[fsortkey(v.z) >> 20], 1u);
    atomicAdd(&lh[fsortkey(v.w) >> 20], 1u);
  }
  __syncthreads();
  unsigned* dst = phist + ((size_t)(p * 8 + blockIdx.x)) * NBIN;
  for (int b = threadIdx.x; b < NBIN; b += 256) dst[b] = lh[b];   // unconditional: no pre-zero
}

// ------- sum partials, find threshold bin B (count(bin >= B) >= kk) --------------------
__global__ __launch_bounds__(256) void k_thresh(const unsigned* phist, int* Bthr) {
  int p = blockIdx.x; int lvl = p % 5;
  unsigned kk = (lvl == 4) ? 768u : 1000u;
  __shared__ unsigned hsum[NBIN];
  __shared__ unsigned csum[256];
  int c = threadIdx.x;
  unsigned tot[16];
#pragma unroll
  for (int k = 0; k < 16; ++k) tot[k] = 0;
  for (int g = 0; g < 8; ++g) {
    const unsigned* hp = phist + ((size_t)(p * 8 + g)) * NBIN + c * 16;
#pragma unroll
    for (int k = 0; k < 16; ++k) tot[k] += hp[k];
  }
  unsigned s = 0;
#pragma unroll
  for (int k = 0; k < 16; ++k) { hsum[c * 16 + k] = tot[k]; s += tot[k]; }
  csum[c] = s;
  __syncthreads();
  if (c == 0) {
    unsigned acc = 0; int B = 0;
    for (int cc = 255; cc >= 0; --cc) {
      if (acc + csum[cc] >= kk) {
        for (int b = 15; b >= 0; --b) {
          acc += hsum[cc * 16 + b];
          if (acc >= kk) { B = cc * 16 + b; break; }
        }
        break;
      }
      acc += csum[cc];
    }
    Bthr[p] = B;
  }
}

// ------- gather: 32 blocks per p; per-block 512-key slice, plain-store count ------------
// NO global atomics, NO zero-init anywhere (r6 lesson: atomics on the wave critical path
// cost ~300cy each; slice ownership removes them entirely).
__global__ __launch_bounds__(256) void k_gather(P5 obj, const int* Bthr,
                                                unsigned* cntB, unsigned long long* ck) {
  int p = blockIdx.y; int img = p / 5, lvl = p % 5;
  int f = 256 >> lvl; int hw = f * f; int n = 3 * hw;
  int B = Bthr[p];
  int tid = threadIdx.x;
  int lane = tid & 63, wv = tid >> 6;
  int shift = 2 * (8 - lvl);
  const float4* src4 = (const float4*)(obj.p[lvl] + (size_t)img * n);
  int n4 = n >> 2;
  int chunk = (n4 + 31) >> 5;                  // gridDim.x == 32
  int e0 = blockIdx.x * chunk, e1 = min(n4, e0 + chunk);
  __shared__ unsigned long long buf[4][BUFCAP];
  __shared__ unsigned wTot[4];
  unsigned wc = 0;                             // wave-uniform running count
  for (int e = e0 + tid; e < e1; e += 256) {
    float4 v = src4[e];
    float vv[4] = {v.x, v.y, v.z, v.w};
#pragma unroll
    for (int j = 0; j < 4; ++j) {
      unsigned sv = fsortkey(vv[j]);
      bool pass = (int)(sv >> 20) >= B;
      unsigned long long m = __ballot(pass);
      if (m) {
        if (pass) {
          unsigned pos = wc + (unsigned)__popcll(m & ((1ULL << lane) - 1ULL));
          int ee = e * 4 + j;
          int a = ee >> shift;                 // ee / hw
          int r = ee & (hw - 1);               // ee % hw
          unsigned kidx = (unsigned)(r * 3 + a); // reference flatten order (y*W+x)*A + a
          unsigned long long key = ((unsigned long long)sv << 32) | (0xFFFFFFFFu - kidx);
          if (pos < BUFCAP) buf[wv][pos] = key; // overflow (pathological only): drop
        }
        wc += (unsigned)__popcll(m);
      }
    }
  }
  if (lane == 0) wTot[wv] = min(wc, (unsigned)BUFCAP);
  __syncthreads();
  unsigned myOff = 0;
  for (int x = 0; x < wv; ++x) myOff += wTot[x];
  unsigned tot4 = wTot[0] + wTot[1] + wTot[2] + wTot[3];
  unsigned long long* dst = ck + ((size_t)p * 32 + blockIdx.x) * SLICE;
  for (unsigned j = lane; j < wTot[wv]; j += 64) {
    unsigned gp = myOff + j;
    if (gp < SLICE) dst[gp] = buf[wv][j];      // coalesced slice flush, no atomics
  }
  if (tid == 0) cntB[p * 32 + blockIdx.x] = min(tot4, (unsigned)SLICE);
}

// ------- FUSED select+decode: parallel one-pass staging, prefetch-then-rank -------------
// Staging: each thread finds its candidate's slice via 5-step LDS binary search -> ALL
// loads issue concurrently (was: 32 serial slice loops x ~600cy L3 latency).
// Rank: delta/anchor loads depend only on the key, not the rank -> issue them BEFORE the
// ~Cc-iteration LDS rank scan; their scattered-HBM latency hides under the scan.
__global__ __launch_bounds__(256) void k_seldec(P5 del, const float* anchors,
                                                const unsigned* cntB,
                                                const unsigned long long* ck,
                                                float* boxP, unsigned long long* keyP) {
  int p = blockIdx.y; int img = p / 5, lvl = p % 5;
  int kk = (lvl == 4) ? 768 : 1000;
  int soff = lvl * 1000;
  int tid = threadIdx.x;
  __shared__ unsigned long long sk[4096];
  __shared__ unsigned offs[33];
  if (tid < 32) {                              // wave-parallel prefix of slice counts
    unsigned v = cntB[p * 32 + tid];
#pragma unroll
    for (int d = 1; d < 32; d <<= 1) {
      unsigned o = __shfl(v, tid - d);
      if (tid >= d) v += o;
    }
    offs[tid + 1] = v;
    if (tid == 0) offs[0] = 0;
  }
  __syncthreads();
  int Cc = min((int)offs[32], 4096);
  if (blockIdx.x * 256 >= Cc) return;
  // ---- parallel staging: one load per candidate, all in flight ----
  for (int x = tid; x < Cc; x += 256) {
    int lo = 0;                                // largest lo in [0,31] with offs[lo] <= x
#pragma unroll
    for (int d = 16; d; d >>= 1)
      if (offs[lo + d] <= (unsigned)x) lo += d;
    sk[x] = ck[((size_t)p * 32 + lo) * SLICE + (x - offs[lo])];
  }
  __syncthreads();
  int c = blockIdx.x * 256 + tid;
  if (c >= Cc) return;
  unsigned long long kc = sk[c];
  // ---- prefetch decode inputs (scattered, cold HBM) before the rank scan ----
  unsigned k = 0xFFFFFFFFu - (unsigned)kc;
  unsigned sv = (unsigned)(kc >> 32);
  int f = 256 >> lvl, hw = f * f;
  const int aoffA[5] = {0, 196608, 245760, 258048, 261120};
  int a = (int)(k % 3u); int r = (int)(k / 3u);
  int y = r >> (8 - lvl); int x = r & (f - 1);
  const float* dp = del.p[lvl] + (size_t)(img * 12 + a * 4) * hw + (size_t)y * f + x;
  float d0 = dp[0], d1 = dp[hw], d2 = dp[2 * hw], d3 = dp[3 * hw];
  const float* ar = anchors + (size_t)(aoffA[lvl] + (int)k) * 4;
  float a0 = ar[0], a1 = ar[1], a2 = ar[2], a3 = ar[3];
  // ---- rank scan (LDS broadcast); HBM latency of the loads above hides under it ----
  int rank = 0;
#pragma unroll 8
  for (int j = 0; j < Cc; ++j) rank += (sk[j] > kc) ? 1 : 0;
  if (rank >= kk) return;
  // ---- decode (numpy-faithful, no FMA contraction) ----
  int i = soff + rank;
  int slot = img * K_SEL + i;
  float w = __fsub_rn(a2, a0), h = __fsub_rn(a3, a1);
  float cx = __fadd_rn(a0, __fmul_rn(0.5f, w));
  float cy = __fadd_rn(a1, __fmul_rn(0.5f, h));
  const float CLIP = 4.135166556742356f;     // log(1000/16)
  float dw = fminf(d2, CLIP), dh = fminf(d3, CLIP);
  float pcx = __fadd_rn(__fmul_rn(d0, w), cx);
  float pcy = __fadd_rn(__fmul_rn(d1, h), cy);
  float pw = __fmul_rn(expf(dw), w);
  float ph = __fmul_rn(expf(dh), h);
  float x1 = __fsub_rn(pcx, __fmul_rn(0.5f, pw));
  float y1 = __fsub_rn(pcy, __fmul_rn(0.5f, ph));
  float x2 = __fadd_rn(pcx, __fmul_rn(0.5f, pw));
  float y2 = __fadd_rn(pcy, __fmul_rn(0.5f, ph));
  float x1c = fminf(fmaxf(x1, 0.0f), 1024.0f);
  float y1c = fminf(fmaxf(y1, 0.0f), 1024.0f);
  float x2c = fminf(fmaxf(x2, 0.0f), 1024.0f);
  float y2c = fminf(fmaxf(y2, 0.0f), 1024.0f);
  bool valid = (__fsub_rn(x2c, x1c) >= 1e-3f) && (__fsub_rn(y2c, y1c) >= 1e-3f);
  float* bp = boxP + (size_t)slot * 4;
  bp[0] = x1c; bp[1] = y1c; bp[2] = x2c; bp[3] = y2c;
  unsigned low = 0xFFFFFFFFu - (unsigned)i;   // pos asc tie-break, unique keys
  keyP[slot] = valid ? (((unsigned long long)sv << 32) | low) : (unsigned long long)low;
}

// ---------------- IoU on offset boxes, bitwise matching reference -----------------------
__device__ __forceinline__ bool iou_gt(float rx1, float ry1, float rx2, float ry2, float rar,
                                       float cx1, float cy1, float cx2, float cy2, float car) {
  float ltx = fmaxf(rx1, cx1), lty = fmaxf(ry1, cy1);
  float rbx = fminf(rx2, cx2), rby = fminf(ry2, cy2);
  float wx = fmaxf(__fsub_rn(rbx, ltx), 0.0f);
  float wy = fmaxf(__fsub_rn(rby, lty), 0.0f);
  float inter = __fmul_rn(wx, wy);
  float denom = __fadd_rn(__fsub_rn(__fadd_rn(rar, car), inter), 1e-9f);
  return __fdiv_rn(inter, denom) > 0.7f;
}

// ---- TRANSPOSED suppression mask T[i] = "which j<i suppress i", triangular-packed ------
__global__ __launch_bounds__(64) void k_lvlmask(const float* boxP, unsigned long long* T) {
  int img = blockIdx.y;
  int q = blockIdx.x;                        // 0..621 per image
  int lvl, q2;
  if (q < 544) { lvl = q / 136; q2 = q - lvl * 136; }
  else         { lvl = 4;       q2 = q - 544; }
  int kk = (lvl == 4) ? 768 : 1000;
  int nch = (kk + 63) >> 6;
  int rb = 0;
  while (q2 >= nch - rb) { q2 -= nch - rb; ++rb; }    // upper-tri (rb, cb>=rb)
  int cb = rb + q2;
  int t = threadIdx.x;
  float off = __fmul_rn((float)lvl, 1025.0f);
  const float4* b4 = (const float4*)boxP + (size_t)img * K_SEL + lvl * 1000;
  __shared__ float rx1s[64], ry1s[64], rx2s[64], ry2s[64], rars[64];
  int j = rb * 64 + t;                       // ROW box staged in LDS
  if (j < kk) {
    float4 bb = b4[j];
    float ox1 = __fadd_rn(bb.x, off), oy1 = __fadd_rn(bb.y, off);
    float ox2 = __fadd_rn(bb.z, off), oy2 = __fadd_rn(bb.w, off);
    rx1s[t] = ox1; ry1s[t] = oy1; rx2s[t] = ox2; ry2s[t] = oy2;
    rars[t] = __fmul_rn(__fsub_rn(ox2, ox1), __fsub_rn(oy2, oy1));
  }
  __syncthreads();
  int i = cb * 64 + t;                       // COLUMN box in registers
  if (i >= kk) return;
  float4 bb = b4[i];
  float cx1 = __fadd_rn(bb.x, off), cy1 = __fadd_rn(bb.y, off);
  float cx2 = __fadd_rn(bb.z, off), cy2 = __fadd_rn(bb.w, off);
  float car = __fmul_rn(__fsub_rn(cx2, cx1), __fsub_rn(cy2, cy1));
  int jmaxR = min(64, kk - rb * 64);
  int jend = (rb == cb) ? min(t, jmaxR) : jmaxR;      // diag: only rows jj < t
  unsigned long long bits = 0;
  for (int jj = 0; jj < jend; ++jj) {
    if (iou_gt(rx1s[jj], ry1s[jj], rx2s[jj], ry2s[jj], rars[jj], cx1, cy1, cx2, cy2, car))
      bits |= (1ULL << jj);
  }
  const int Pt[16] = {0, 1, 4, 7, 12, 17, 24, 31, 40, 49, 60, 71, 84, 97, 112, 127};
  int sc = (cb + 1) | 1;
  T[(size_t)(img * 5 + lvl) * TPAD + 64 * Pt[cb] + t * sc + rb] = bits;
}

// ---- per-level greedy NMS: LDS-staged T + single-wave serial chunk sweep (r4-proven) ---
__global__ __launch_bounds__(256) void k_lvlnms(const unsigned long long* keyP,
                                                const unsigned long long* Tg_,
                                                unsigned long long* keepw) {
  int p = blockIdx.x; int img = p / 5, lvl = p % 5;
  int kk = (lvl == 4) ? 768 : 1000;
  int tw = (lvl == 4) ? 5376 : TPAD;         // words used (lvl4: chunks 0..11 only)
  int tid = threadIdx.x;
  __shared__ __align__(16) unsigned long long Ts[TPAD];   // 72 KiB
  const unsigned long long* Tg = Tg_ + (size_t)p * TPAD;
  const unsigned long long* kp = keyP + (size_t)img * K_SEL + lvl * 1000;
  // wave0: prefetch validity bits for all 16 chunks (overlaps the staging loop's loads)
  unsigned vmask = 0;
  if (tid < 64) {
#pragma unroll
    for (int c = 0; c < 16; ++c) {
      int i = c * 64 + tid;
      bool v = (i < kk) && ((kp[min(i, kk - 1)] >> 32) != 0ULL);
      vmask |= v ? (1u << c) : 0u;
    }
  }
  // staging: x4-batched 16B loads (4 in flight) to hide L2/HBM latency
  {
    const ulonglong2* Tg2 = (const ulonglong2*)Tg;
    ulonglong2* Ts2 = (ulonglong2*)Ts;
    int nv = tw >> 1;
    for (int x = tid; x < nv; x += 1024) {
      int x1i = x + 256, x2i = x + 512, x3i = x + 768;
      ulonglong2 a0 = Tg2[x], a1 = {}, a2 = {}, a3 = {};
      if (x1i < nv) a1 = Tg2[x1i];
      if (x2i < nv) a2 = Tg2[x2i];
      if (x3i < nv) a3 = Tg2[x3i];
      Ts2[x] = a0;
      if (x1i < nv) Ts2[x1i] = a1;
      if (x2i < nv) Ts2[x2i] = a2;
      if (x3i < nv) Ts2[x3i] = a3;
    }
  }
  __syncthreads();
  if (tid >= 64) return;                     // waves 1-3 done (no further barriers)
  int t = tid;
  const int Pt[16] = {0, 1, 4, 7, 12, 17, 24, 31, 40, 49, 60, 71, 84, 97, 112, 127};
  unsigned long long kw[16];
#pragma unroll
  for (int w = 0; w < 16; ++w) kw[w] = 0ULL;
#pragma unroll
  for (int c = 0; c < 16; ++c) {
    if (c * 64 < kk) {
      int base = 64 * Pt[c] + t * ((c + 1) | 1);
      unsigned long long tv[16];
#pragma unroll
      for (int w = 0; w < 16; ++w) tv[w] = Ts[base + w]; // batch reads; w>c garbage, masked
      unsigned long long a = 0;
#pragma unroll
      for (int w = 0; w < 16; ++w) a |= tv[w] & kw[w];   // kw[w]=0 for w>=c
      unsigned long long colT = tv[c];                   // diag word: suppressors j<t in chunk
      bool alive = ((vmask >> c) & 1u) && (a == 0ULL);
      unsigned long long keepm = 0ULL;
      unsigned long long actm = __ballot(alive);
      while (actm) {
        bool cank = alive && ((colT & actm) == 0ULL);    // no alive suppressor below t
        unsigned long long newk = __ballot(cank);
        keepm |= newk;
        alive = alive && !cank && ((colT & newk) == 0ULL);
        actm = __ballot(alive);
      }
      kw[c] = keepm;                                     // static index (unrolled)
    }
  }
  if (t == 0) {
#pragma unroll
    for (int c = 0; c < 16; ++c) keepw[(size_t)p * 16 + c] = kw[c];  // uniform ballot values
  }
}

// ---- merge: 40 blocks = (img,lvl); each compacts all levels (coalesced) but ranks only
// ---- its own level's kept entries (4 interleaved binary searches, short LDS chains) ----
__global__ __launch_bounds__(256) void k_merge(const unsigned long long* keyP, const float* boxP,
                                               const unsigned long long* keepw, float* out) {
  int p = blockIdx.x; int img = p / 5, lvl = p % 5;
  int tid = threadIdx.x;
  __shared__ unsigned long long lkey[5000];   // level l at l*1000: compacted kept keys (desc)
  __shared__ int lpos[5000];                  // original within-image slot
  __shared__ int wp[5][17];                   // per-level word-prefix popcounts
  __shared__ unsigned long long kwS[80];
  for (int x = tid; x < 80; x += 256) {
    kwS[x] = keepw[(size_t)img * 80 + x];     // all 16 words written by k_lvlnms
  }
  __syncthreads();
  if (tid < 5) {
    int acc = 0;
    for (int w = 0; w < 16; ++w) { wp[tid][w] = acc; acc += (int)__popcll(kwS[tid * 16 + w]); }
    wp[tid][16] = acc;
  }
  __syncthreads();
  const unsigned long long* kp = keyP + (size_t)img * K_SEL;
  for (int i = tid; i < K_SEL; i += 256) {
    int l = (i < 4000) ? i / 1000 : 4;
    int li = i - l * 1000;
    unsigned long long wmask = kwS[l * 16 + (li >> 6)];
    if ((wmask >> (li & 63)) & 1ULL) {
      int j = wp[l][li >> 6] + (int)__popcll(wmask & ((1ULL << (li & 63)) - 1ULL));
      lkey[l * 1000 + j] = kp[i];
      lpos[l * 1000 + j] = i;
    }
  }
  __syncthreads();
  const float4* b4 = (const float4*)boxP + (size_t)img * K_SEL;
  float4* out4 = (float4*)out + (size_t)img * 1000;
  int kn = wp[lvl][16];
  for (int j = tid; j < kn; j += 256) {
    unsigned long long key = lkey[lvl * 1000 + j];
    int grank = j;
#pragma unroll
    for (int l2 = 0; l2 < 5; ++l2) {
      if (l2 == lvl) continue;
      int lo = 0, hi = wp[l2][16];
      const unsigned long long* a = &lkey[l2 * 1000];
      while (lo < hi) { int mid = (lo + hi) >> 1; if (a[mid] > key) lo = mid + 1; else hi = mid; }
      grank += lo;                            // count of keys > key in level l2
    }
    if (grank < 1000) out4[grank] = b4[lpos[lvl * 1000 + j]];
  }
  if (lvl == 0) {                             // pad region [KT,1000) has no grank: disjoint
    int KT = wp[0][16] + wp[1][16] + wp[2][16] + wp[3][16] + wp[4][16];
    for (int s = min(KT, 1000) + tid; s < 1000; s += 256)
      out4[s] = make_float4(0.f, 0.f, 0.f, 0.f);          // zero-pad tail
  }
}

extern "C" void kernel_launch(void* const* d_in, const int* in_sizes, int n_in,
                              void* d_out, int out_size, void* d_ws, size_t ws_size,
                              hipStream_t stream) {
  (void)in_sizes; (void)n_in;
  // setup_inputs() dict order is INTERLEAVED: obj_l0, delta_l0, obj_l1, delta_l1, ..., anchors
  P5 obj, del;
  for (int i = 0; i < 5; ++i) {
    obj.p[i] = (const float*)d_in[2 * i];
    del.p[i] = (const float*)d_in[2 * i + 1];
  }
  const float* anchors = (const float*)d_in[10];
  float* out = (float*)d_out;
  char* ws = (char*)d_ws;

  // ws layout (bytes) — nothing needs zero-init
  unsigned* cntB              = (unsigned*)(ws + 0);                   // 5120
  int* Bthr                   = (int*)(ws + 5120);                     // 160 -> 5280
  unsigned long long* candK   = (unsigned long long*)(ws + 8192);      // 5242880 -> 5251072
  float* boxP                 = (float*)(ws + 5548544);                // 610304 -> 6158848
  unsigned long long* keyP    = (unsigned long long*)(ws + 6158848);   // 305152 -> 6464000
  unsigned long long* keepw   = (unsigned long long*)(ws + 6464000);   // 5120 -> 6469120
  unsigned long long* T       = (unsigned long long*)(ws + 6469120);   // 2949120 -> 9418240
  unsigned* phist             = (unsigned*)(ws + 6469120);             // overlay on T (dead before k_lvlmask): 5242880 -> 11712000
  const size_t NEED = 11712000ULL;
  if (ws_size < NEED) { hipMemsetAsync(d_out, 0, (size_t)out_size * 4, stream); return; }

  k_hist    <<<dim3(8, 40), 256, 0, stream>>>(obj, phist);
  k_thresh  <<<40, 256, 0, stream>>>(phist, Bthr);
  k_gather  <<<dim3(32, 40), 256, 0, stream>>>(obj, Bthr, cntB, candK);
  k_seldec  <<<dim3(16, 40), 256, 0, stream>>>(del, anchors, cntB, candK, boxP, keyP);
  k_lvlmask <<<dim3(622, 8), 64, 0, stream>>>(boxP, T);
  k_lvlnms  <<<40, 256, 0, stream>>>(keyP, T, keepw);
  k_merge   <<<40, 256, 0, stream>>>(keyP, boxP, keepw, out);
}